// Round 19
// baseline (331.875 us; speedup 1.0000x reference)
//
#include <hip/hip_runtime.h>
#include <stdint.h>

typedef __attribute__((ext_vector_type(4))) float f32x4;
typedef __attribute__((ext_vector_type(8))) short bf16x8;

#define MFMA_BF16 __builtin_amdgcn_mfma_f32_16x16x32_bf16

__device__ __forceinline__ unsigned short f2bf(float f) {
  union { float f; uint32_t u; } a; a.f = f;
  uint32_t u = a.u;
  uint32_t r = (u + 0x7FFFu + ((u >> 16) & 1u)) >> 16;
  return (unsigned short)r;
}

__device__ __forceinline__ bf16x8 cvt8(const float4 v0, const float4 v1) {
  bf16x8 o;
  o[0] = (short)f2bf(v0.x); o[1] = (short)f2bf(v0.y);
  o[2] = (short)f2bf(v0.z); o[3] = (short)f2bf(v0.w);
  o[4] = (short)f2bf(v1.x); o[5] = (short)f2bf(v1.y);
  o[6] = (short)f2bf(v1.z); o[7] = (short)f2bf(v1.w);
  return o;
}

// Merged pack, 16B-vectorized.
// chunk q in [0, 2097152): A ([x|h] -> bf16 A[4096][4096] row-major).
// chunk q in [2097152, 6291456): W -> gate-interleaved Wp[8192][4096].
// Packed row p: bn=p>>8, r=p&255; wn=r>>6, gate=(r>>4)&3, hlow=r&15;
//   H = bn*64 + wn*16 + hlow; cols 0..2047 = Wx_g[H], 2048.. = Wh_g[H].
// (fragment n of wave wn == gate n -> register-local LSTM epilogue)
__global__ void pack_all_kernel(const float4* __restrict__ x, const float4* __restrict__ hh,
                                const float* __restrict__ Wii, const float* __restrict__ Wif,
                                const float* __restrict__ Wig, const float* __restrict__ Wio,
                                const float* __restrict__ Whi, const float* __restrict__ Whf,
                                const float* __restrict__ Whg, const float* __restrict__ Who,
                                bf16x8* __restrict__ A, bf16x8* __restrict__ Wp) {
  const int total = 6291456;
  for (int q = blockIdx.x * blockDim.x + threadIdx.x; q < total; q += gridDim.x * blockDim.x) {
    if (q < 2097152) {
      int row = q >> 9, c8 = q & 511;
      const float4* src = (c8 < 256) ? &x[row * 512 + c8 * 2] : &hh[row * 512 + (c8 - 256) * 2];
      A[q] = cvt8(src[0], src[1]);
    } else {
      int wq = q - 2097152;
      int p = wq >> 9, k8 = wq & 511;
      int r = p & 255;
      int g = (r >> 4) & 3;
      int H = ((p >> 8) << 6) | ((r >> 6) << 4) | (r & 15);
      const float* src;
      int k;
      if (k8 < 256) {
        src = (g == 0) ? Wii : (g == 1) ? Wif : (g == 2) ? Wig : Wio; k = k8 << 3;
      } else {
        src = (g == 0) ? Whi : (g == 1) ? Whf : (g == 2) ? Whg : Who; k = (k8 - 256) << 3;
      }
      const float4 v0 = *(const float4*)&src[(size_t)H * 2048 + k];
      const float4 v1 = *(const float4*)&src[(size_t)H * 2048 + k + 4];
      Wp[wq] = cvt8(v0, v1);
    }
  }
}

// TWO-BLOCK-PER-CU GEMM: tile 128x256, BK=32, 8 waves (2Mx4N), per-wave
// 64x64 (acc = 64 VGPR). LDS 48 KiB/block -> 2 blocks/CU in INDEPENDENT
// barrier domains: one block's vmcnt(0)+barrier drain hides under the other
// block's compute (m114 cross-wave pipe overlap). Free-drift tile: stage T+1
// into other buf at top (3 gloads/wave), 8 frag reads, 16 MFMA, drain+bar.
// 64B-row LDS: phys chunk = logical ^ (row&3) -> balanced 8 lanes/bank-quad.
#define AS1 __attribute__((address_space(1)))
#define AS3 __attribute__((address_space(3)))
#define GLD(srcp, dstE)                                                         \
  __builtin_amdgcn_global_load_lds((const AS1 void*)(srcp),                     \
                                   (AS3 void*)(&smem[dstE]), 16, 0, 0)

// Stage tile T_ into buffer obuf_: A 1 gload (16 rows/wave), B 2 gloads.
#define STAGE(T_, obuf_)                                                        \
  {                                                                             \
    const size_t kO_ = (size_t)(T_) * 32;                                       \
    GLD(aS + kO_, (obuf_) + dA);                                                \
    GLD(bS + kO_, (obuf_) + dB);                                                \
    GLD(bS + (size_t)16 * 4096 + kO_, (obuf_) + dB + 512);                      \
  }

#define TILE(T_, buf_, obuf_, DOST_, SYNC_)                                     \
  {                                                                             \
    if (DOST_) { STAGE((T_) + 1, obuf_); }                                      \
    bf16x8 af[4], bf[4];                                                        \
    _Pragma("unroll") for (int m = 0; m < 4; ++m)                               \
      af[m] = *(const bf16x8*)&smem[(buf_) + aRb + m * 512 + colE];             \
    _Pragma("unroll") for (int n = 0; n < 4; ++n)                               \
      bf[n] = *(const bf16x8*)&smem[(buf_) + bRb + n * 512 + colE];             \
    __builtin_amdgcn_s_setprio(1);                                              \
    _Pragma("unroll") for (int m = 0; m < 4; ++m)                               \
      _Pragma("unroll") for (int n = 0; n < 4; ++n)                             \
        acc[m][n] = MFMA_BF16(af[m], bf[n], acc[m][n], 0, 0, 0);                \
    __builtin_amdgcn_s_setprio(0);                                              \
    if (SYNC_) {                                                                \
      asm volatile("s_waitcnt vmcnt(0)" ::: "memory");                          \
      __builtin_amdgcn_s_barrier();                                             \
    }                                                                           \
  }

__global__ __launch_bounds__(512, 4)
void lstm_gemm_kernel(const ushort* __restrict__ A, const ushort* __restrict__ Wp,
                      const float* __restrict__ c,
                      const float* __restrict__ bii, const float* __restrict__ bif_,
                      const float* __restrict__ big_, const float* __restrict__ bio_,
                      const float* __restrict__ bhi, const float* __restrict__ bhf,
                      const float* __restrict__ bhg, const float* __restrict__ bho,
                      float* __restrict__ out) {
  __shared__ ushort smem[24576];  // 48 KiB: 2 bufs x (A[128][32] + B[256][32])
  const int tid = threadIdx.x;
  const int lane = tid & 63, w = tid >> 6;
  const int wm = w >> 2, wn = w & 3;

  // bn-major XCD mapping: 1024 blocks; XCD x owns bn in [x*4, x*4+4).
  const int bid = blockIdx.x;
  const int xcd = bid & 7, qq = bid >> 3;      // qq in [0,128)
  const int bn = (xcd << 2) | (qq >> 5);       // 4 N-panels per XCD
  const int bm = qq & 31;

  const int laneRow = lane & 15, lane16 = lane >> 4;
  // Fragment read: logical chunk lane16 of row (.. + laneRow);
  // phys = logical ^ (row&3); row&3 == laneRow&3 (16-row-aligned frags).
  const int colE = ((lane16 ^ (laneRow & 3)) << 3);   // elems
  const int aRb = (wm * 64 + laneRow) * 32;           // + buf + m*512 + colE
  const int bRb = 4096 + (wn * 64 + laneRow) * 32;    // + buf + n*512 + colE

  // DMA: lane l -> LDS row +(l>>2), phys chunk l&3 holding logical
  // (l&3)^((l>>2)&3) -> pre-swizzled global source chunk.
  const int chunkOff = ((lane & 3) ^ ((lane >> 2) & 3)) << 3;
  const ushort* aS = A + (size_t)(bm * 128 + 16 * w + (lane >> 2)) * 4096 + chunkOff;
  const ushort* bS = Wp + (size_t)(bn * 256 + 32 * w + (lane >> 2)) * 4096 + chunkOff;
  const int dA = w * 512;           // A region at 0 (+obuf)
  const int dB = 4096 + w * 1024;   // B region at 4096 (+obuf)

  f32x4 acc[4][4];
#pragma unroll
  for (int i = 0; i < 4; i++)
#pragma unroll
    for (int j = 0; j < 4; j++) acc[i][j] = (f32x4){0.f, 0.f, 0.f, 0.f};

  // Prologue: stage tile 0 into buf0.
  STAGE(0, 0);
  asm volatile("s_waitcnt vmcnt(0)" ::: "memory");
  __builtin_amdgcn_s_barrier();

  // 128 K-tiles (BK=32), 2x unrolled for static buffer offsets.
#pragma unroll 1
  for (int T = 0; T < 126; T += 2) {
    TILE(T, 0, 12288, true, true);
    TILE(T + 1, 12288, 0, true, true);
  }
  TILE(126, 0, 12288, true, true);   // stages tile 127
  TILE(127, 12288, 0, false, false); // final, no sync

  // Fused LSTM epilogue: acc[mi][gate][rr] register-local per (row, hcol).
  const int hcol = bn * 64 + wn * 16 + laneRow;
  const float bI = bii[hcol] + bhi[hcol];
  const float bF = bif_[hcol] + bhf[hcol];
  const float bG = big_[hcol] + bhg[hcol];
  const float bO = bio_[hcol] + bho[hcol];
#pragma unroll
  for (int mi = 0; mi < 4; ++mi) {
    const int rowBase = bm * 128 + wm * 64 + mi * 16 + lane16 * 4;
#pragma unroll
    for (int rr = 0; rr < 4; ++rr) {
      const int row = rowBase + rr;
      const float ii = acc[mi][0][rr] + bI;
      const float ff = acc[mi][1][rr] + bF;
      const float gg = acc[mi][2][rr] + bG;
      const float oo = acc[mi][3][rr] + bO;
      const float iv = 1.f / (1.f + __expf(-ii));
      const float fv = 1.f / (1.f + __expf(-ff));
      const float gv = tanhf(gg);
      const float ov = 1.f / (1.f + __expf(-oo));
      const float cv = c[(size_t)row * 2048 + hcol];
      const float cn = fv * cv + iv * gv;
      const float hn = ov * tanhf(cn);
      out[(size_t)row * 2048 + hcol] = hn;
      out[(size_t)8388608 + (size_t)row * 2048 + hcol] = cn;
    }
  }
}

extern "C" void kernel_launch(void* const* d_in, const int* in_sizes, int n_in,
                              void* d_out, int out_size, void* d_ws, size_t ws_size,
                              hipStream_t stream) {
  const float* x = (const float*)d_in[0];
  const float* h = (const float*)d_in[1];
  const float* c = (const float*)d_in[2];
  const float* Wii = (const float*)d_in[3];  const float* bii = (const float*)d_in[4];
  const float* Wif = (const float*)d_in[5];  const float* bif_ = (const float*)d_in[6];
  const float* Wig = (const float*)d_in[7];  const float* big_ = (const float*)d_in[8];
  const float* Wio = (const float*)d_in[9];  const float* bio_ = (const float*)d_in[10];
  const float* Whi = (const float*)d_in[11]; const float* bhi = (const float*)d_in[12];
  const float* Whf = (const float*)d_in[13]; const float* bhf = (const float*)d_in[14];
  const float* Whg = (const float*)d_in[15]; const float* bhg = (const float*)d_in[16];
  const float* Who = (const float*)d_in[17]; const float* bho = (const float*)d_in[18];

  ushort* Abf = (ushort*)d_ws;                    // 4096*4096 bf16
  ushort* Wpk = Abf + (size_t)4096 * 4096;        // 8192*4096 bf16
  float* out = (float*)d_out;

  pack_all_kernel<<<3072, 256, 0, stream>>>((const float4*)x, (const float4*)h,
                                            Wii, Wif, Wig, Wio, Whi, Whf, Whg, Who,
                                            (bf16x8*)Abf, (bf16x8*)Wpk);
  lstm_gemm_kernel<<<1024, 512, 0, stream>>>(Abf, Wpk, c,
                                             bii, bif_, big_, bio_, bhi, bhf, bhg, bho, out);
}

// Round 20
// 328.240 us; speedup vs baseline: 1.0111x; 1.0111x over previous
//
#include <hip/hip_runtime.h>
#include <stdint.h>

typedef __attribute__((ext_vector_type(4))) float f32x4;
typedef __attribute__((ext_vector_type(8))) short bf16x8;

#define MFMA_BF16 __builtin_amdgcn_mfma_f32_16x16x32_bf16

__device__ __forceinline__ unsigned short f2bf(float f) {
  union { float f; uint32_t u; } a; a.f = f;
  uint32_t u = a.u;
  uint32_t r = (u + 0x7FFFu + ((u >> 16) & 1u)) >> 16;
  return (unsigned short)r;
}

__device__ __forceinline__ bf16x8 cvt8(const float4 v0, const float4 v1) {
  bf16x8 o;
  o[0] = (short)f2bf(v0.x); o[1] = (short)f2bf(v0.y);
  o[2] = (short)f2bf(v0.z); o[3] = (short)f2bf(v0.w);
  o[4] = (short)f2bf(v1.x); o[5] = (short)f2bf(v1.y);
  o[6] = (short)f2bf(v1.z); o[7] = (short)f2bf(v1.w);
  return o;
}

// Merged pack, 16B-vectorized (unchanged from R19).
// chunk q in [0, 2097152): A ([x|h] -> bf16 A[4096][4096] row-major).
// chunk q in [2097152, 6291456): W -> gate-interleaved Wp[8192][4096].
// Packed row p: bn=p>>8, r=p&255; wn=r>>6, gate=(r>>4)&3, hlow=r&15;
//   H = bn*64 + wn*16 + hlow; cols 0..2047 = Wx_g[H], 2048.. = Wh_g[H].
__global__ void pack_all_kernel(const float4* __restrict__ x, const float4* __restrict__ hh,
                                const float* __restrict__ Wii, const float* __restrict__ Wif,
                                const float* __restrict__ Wig, const float* __restrict__ Wio,
                                const float* __restrict__ Whi, const float* __restrict__ Whf,
                                const float* __restrict__ Whg, const float* __restrict__ Who,
                                bf16x8* __restrict__ A, bf16x8* __restrict__ Wp) {
  const int total = 6291456;
  for (int q = blockIdx.x * blockDim.x + threadIdx.x; q < total; q += gridDim.x * blockDim.x) {
    if (q < 2097152) {
      int row = q >> 9, c8 = q & 511;
      const float4* src = (c8 < 256) ? &x[row * 512 + c8 * 2] : &hh[row * 512 + (c8 - 256) * 2];
      A[q] = cvt8(src[0], src[1]);
    } else {
      int wq = q - 2097152;
      int p = wq >> 9, k8 = wq & 511;
      int r = p & 255;
      int g = (r >> 4) & 3;
      int H = ((p >> 8) << 6) | ((r >> 6) << 4) | (r & 15);
      const float* src;
      int k;
      if (k8 < 256) {
        src = (g == 0) ? Wii : (g == 1) ? Wif : (g == 2) ? Wig : Wio; k = k8 << 3;
      } else {
        src = (g == 0) ? Whi : (g == 1) ? Whf : (g == 2) ? Whg : Who; k = (k8 - 256) << 3;
      }
      const float4 v0 = *(const float4*)&src[(size_t)H * 2048 + k];
      const float4 v1 = *(const float4*)&src[(size_t)H * 2048 + k + 4];
      Wp[wq] = cvt8(v0, v1);
    }
  }
}

// TWO-BLOCK-PER-CU GEMM, conflict-fixed swizzle.
// Tile 128x256, BK=32, 8 waves (2Mx4N), per-wave 64x64 (acc = 64 VGPR).
// LDS 48 KiB/block -> 2 blocks/CU (independent barrier domains).
// 64B-row LDS swizzle (CORRECTED): phys chunk = logical ^ ((row>>1)&3).
// Bank check: 8-lane phase (rows r..r+7) -> banks 16*(row%2)+4*chunk cover
// all 32 banks for every lane16 class (exhaustively verified).
#define AS1 __attribute__((address_space(1)))
#define AS3 __attribute__((address_space(3)))
#define GLD(srcp, dstE)                                                         \
  __builtin_amdgcn_global_load_lds((const AS1 void*)(srcp),                     \
                                   (AS3 void*)(&smem[dstE]), 16, 0, 0)

// Stage tile T_ into buffer obuf_: A 1 gload (16 rows/wave), B 2 gloads.
#define STAGE(T_, obuf_)                                                        \
  {                                                                             \
    const size_t kO_ = (size_t)(T_) * 32;                                       \
    GLD(aS + kO_, (obuf_) + dA);                                                \
    GLD(bS + kO_, (obuf_) + dB);                                                \
    GLD(bS + (size_t)16 * 4096 + kO_, (obuf_) + dB + 512);                      \
  }

#define TILE(T_, buf_, obuf_, DOST_, SYNC_)                                     \
  {                                                                             \
    if (DOST_) { STAGE((T_) + 1, obuf_); }                                      \
    bf16x8 af[4], bf[4];                                                        \
    _Pragma("unroll") for (int m = 0; m < 4; ++m)                               \
      af[m] = *(const bf16x8*)&smem[(buf_) + aRb + m * 512 + colE];             \
    _Pragma("unroll") for (int n = 0; n < 4; ++n)                               \
      bf[n] = *(const bf16x8*)&smem[(buf_) + bRb + n * 512 + colE];             \
    __builtin_amdgcn_s_setprio(1);                                              \
    _Pragma("unroll") for (int m = 0; m < 4; ++m)                               \
      _Pragma("unroll") for (int n = 0; n < 4; ++n)                             \
        acc[m][n] = MFMA_BF16(af[m], bf[n], acc[m][n], 0, 0, 0);                \
    __builtin_amdgcn_s_setprio(0);                                              \
    if (SYNC_) {                                                                \
      asm volatile("s_waitcnt vmcnt(0)" ::: "memory");                          \
      __builtin_amdgcn_s_barrier();                                             \
    }                                                                           \
  }

__global__ __launch_bounds__(512, 4)
void lstm_gemm_kernel(const ushort* __restrict__ A, const ushort* __restrict__ Wp,
                      const float* __restrict__ c,
                      const float* __restrict__ bii, const float* __restrict__ bif_,
                      const float* __restrict__ big_, const float* __restrict__ bio_,
                      const float* __restrict__ bhi, const float* __restrict__ bhf,
                      const float* __restrict__ bhg, const float* __restrict__ bho,
                      float* __restrict__ out) {
  __shared__ ushort smem[24576];  // 48 KiB: 2 bufs x (A[128][32] + B[256][32])
  const int tid = threadIdx.x;
  const int lane = tid & 63, w = tid >> 6;
  const int wm = w >> 2, wn = w & 3;

  // bn-major XCD mapping: 1024 blocks; XCD x owns bn in [x*4, x*4+4).
  const int bid = blockIdx.x;
  const int xcd = bid & 7, qq = bid >> 3;      // qq in [0,128)
  const int bn = (xcd << 2) | (qq >> 5);       // 4 N-panels per XCD
  const int bm = qq & 31;

  const int laneRow = lane & 15, lane16 = lane >> 4;
  // CORRECTED read swizzle: phys chunk = lane16 ^ ((row>>1)&3).
  // (frag row = 16-aligned base + laneRow -> (row>>1)&3 == (laneRow>>1)&3)
  const int colE = ((lane16 ^ ((laneRow >> 1) & 3)) << 3);   // elems
  const int aRb = (wm * 64 + laneRow) * 32;           // + buf + m*512 + colE
  const int bRb = 4096 + (wn * 64 + laneRow) * 32;    // + buf + n*512 + colE

  // DMA: lane l -> LDS row +(l>>2), phys chunk l&3 holding logical
  // (l&3)^((l>>3)&3) -> pre-swizzled global source chunk (inverse of read).
  const int chunkOff = ((lane & 3) ^ ((lane >> 3) & 3)) << 3;
  const ushort* aS = A + (size_t)(bm * 128 + 16 * w + (lane >> 2)) * 4096 + chunkOff;
  const ushort* bS = Wp + (size_t)(bn * 256 + 32 * w + (lane >> 2)) * 4096 + chunkOff;
  const int dA = w * 512;           // A region at 0 (+obuf)
  const int dB = 4096 + w * 1024;   // B region at 4096 (+obuf)

  f32x4 acc[4][4];
#pragma unroll
  for (int i = 0; i < 4; i++)
#pragma unroll
    for (int j = 0; j < 4; j++) acc[i][j] = (f32x4){0.f, 0.f, 0.f, 0.f};

  // Prologue: stage tile 0 into buf0.
  STAGE(0, 0);
  asm volatile("s_waitcnt vmcnt(0)" ::: "memory");
  __builtin_amdgcn_s_barrier();

  // 128 K-tiles (BK=32), 2x unrolled for static buffer offsets.
#pragma unroll 1
  for (int T = 0; T < 126; T += 2) {
    TILE(T, 0, 12288, true, true);
    TILE(T + 1, 12288, 0, true, true);
  }
  TILE(126, 0, 12288, true, true);   // stages tile 127
  TILE(127, 12288, 0, false, false); // final, no sync

  // Fused LSTM epilogue: acc[mi][gate][rr] register-local per (row, hcol).
  const int hcol = bn * 64 + wn * 16 + laneRow;
  const float bI = bii[hcol] + bhi[hcol];
  const float bF = bif_[hcol] + bhf[hcol];
  const float bG = big_[hcol] + bhg[hcol];
  const float bO = bio_[hcol] + bho[hcol];
#pragma unroll
  for (int mi = 0; mi < 4; ++mi) {
    const int rowBase = bm * 128 + wm * 64 + mi * 16 + lane16 * 4;
#pragma unroll
    for (int rr = 0; rr < 4; ++rr) {
      const int row = rowBase + rr;
      const float ii = acc[mi][0][rr] + bI;
      const float ff = acc[mi][1][rr] + bF;
      const float gg = acc[mi][2][rr] + bG;
      const float oo = acc[mi][3][rr] + bO;
      const float iv = 1.f / (1.f + __expf(-ii));
      const float fv = 1.f / (1.f + __expf(-ff));
      const float gv = tanhf(gg);
      const float ov = 1.f / (1.f + __expf(-oo));
      const float cv = c[(size_t)row * 2048 + hcol];
      const float cn = fv * cv + iv * gv;
      const float hn = ov * tanhf(cn);
      out[(size_t)row * 2048 + hcol] = hn;
      out[(size_t)8388608 + (size_t)row * 2048 + hcol] = cn;
    }
  }
}

extern "C" void kernel_launch(void* const* d_in, const int* in_sizes, int n_in,
                              void* d_out, int out_size, void* d_ws, size_t ws_size,
                              hipStream_t stream) {
  const float* x = (const float*)d_in[0];
  const float* h = (const float*)d_in[1];
  const float* c = (const float*)d_in[2];
  const float* Wii = (const float*)d_in[3];  const float* bii = (const float*)d_in[4];
  const float* Wif = (const float*)d_in[5];  const float* bif_ = (const float*)d_in[6];
  const float* Wig = (const float*)d_in[7];  const float* big_ = (const float*)d_in[8];
  const float* Wio = (const float*)d_in[9];  const float* bio_ = (const float*)d_in[10];
  const float* Whi = (const float*)d_in[11]; const float* bhi = (const float*)d_in[12];
  const float* Whf = (const float*)d_in[13]; const float* bhf = (const float*)d_in[14];
  const float* Whg = (const float*)d_in[15]; const float* bhg = (const float*)d_in[16];
  const float* Who = (const float*)d_in[17]; const float* bho = (const float*)d_in[18];

  ushort* Abf = (ushort*)d_ws;                    // 4096*4096 bf16
  ushort* Wpk = Abf + (size_t)4096 * 4096;        // 8192*4096 bf16
  float* out = (float*)d_out;

  pack_all_kernel<<<3072, 256, 0, stream>>>((const float4*)x, (const float4*)h,
                                            Wii, Wif, Wig, Wio, Whi, Whf, Whg, Who,
                                            (bf16x8*)Abf, (bf16x8*)Wpk);
  lstm_gemm_kernel<<<1024, 512, 0, stream>>>(Abf, Wpk, c,
                                             bii, bif_, big_, bio_, bhi, bhf, bhg, bho, out);
}

// Round 21
// 297.841 us; speedup vs baseline: 1.1143x; 1.1021x over previous
//
#include <hip/hip_runtime.h>
#include <stdint.h>

typedef __attribute__((ext_vector_type(4))) float f32x4;
typedef __attribute__((ext_vector_type(8))) short bf16x8;

#define MFMA_BF16 __builtin_amdgcn_mfma_f32_16x16x32_bf16

__device__ __forceinline__ unsigned short f2bf(float f) {
  union { float f; uint32_t u; } a; a.f = f;
  uint32_t u = a.u;
  uint32_t r = (u + 0x7FFFu + ((u >> 16) & 1u)) >> 16;
  return (unsigned short)r;
}

__device__ __forceinline__ bf16x8 cvt8(const float4 v0, const float4 v1) {
  bf16x8 o;
  o[0] = (short)f2bf(v0.x); o[1] = (short)f2bf(v0.y);
  o[2] = (short)f2bf(v0.z); o[3] = (short)f2bf(v0.w);
  o[4] = (short)f2bf(v1.x); o[5] = (short)f2bf(v1.y);
  o[6] = (short)f2bf(v1.z); o[7] = (short)f2bf(v1.w);
  return o;
}

// Merged pack, 16B-write vectorized (8 bf16 per lane-iteration).
// chunk q in [0, 2097152): A ([x|h] -> bf16 A[4096][4096], row-major).
// chunk q in [2097152, 6291456): W -> gate-interleaved Wp[8192][4096]:
//   packed row p: r=p&255; gate g=((r>>7)<<1)|((r>>4)&1);
//   H=((p>>8)<<6)|(((r>>5)&3)<<4)|(r&15); cols 0..2047=Wx_g[H], 2048..=Wh_g[H].
__global__ void pack_all_kernel(const float4* __restrict__ x, const float4* __restrict__ hh,
                                const float* __restrict__ Wii, const float* __restrict__ Wif,
                                const float* __restrict__ Wig, const float* __restrict__ Wio,
                                const float* __restrict__ Whi, const float* __restrict__ Whf,
                                const float* __restrict__ Whg, const float* __restrict__ Who,
                                bf16x8* __restrict__ A, bf16x8* __restrict__ Wp) {
  const int total = 6291456;
  for (int q = blockIdx.x * blockDim.x + threadIdx.x; q < total; q += gridDim.x * blockDim.x) {
    if (q < 2097152) {
      int row = q >> 9, c8 = q & 511;   // 512 chunks of 8 per 4096-col row
      const float4* src = (c8 < 256) ? &x[row * 512 + c8 * 2] : &hh[row * 512 + (c8 - 256) * 2];
      A[q] = cvt8(src[0], src[1]);
    } else {
      int wq = q - 2097152;
      int p = wq >> 9, k8 = wq & 511;
      int r = p & 255;
      int g = ((r >> 7) << 1) | ((r >> 4) & 1);
      int H = ((p >> 8) << 6) | (((r >> 5) & 3) << 4) | (r & 15);
      const float* src;
      int k;
      if (k8 < 256) {
        src = (g == 0) ? Wii : (g == 1) ? Wif : (g == 2) ? Wig : Wio; k = k8 << 3;
      } else {
        src = (g == 0) ? Whi : (g == 1) ? Whf : (g == 2) ? Whg : Who; k = (k8 - 256) << 3;
      }
      const float4 v0 = *(const float4*)&src[(size_t)H * 2048 + k];
      const float4 v1 = *(const float4*)&src[(size_t)H * 2048 + k + 4];
      Wp[wq] = cvt8(v0, v1);
    }
  }
}

// R13 GEMM (best measured: 263 us, MfmaUtil 47.2%, 0 conflicts).
// 3-BARRIER TILE. 256x256, BK=64, 8 waves (2Mx4N), per-wave 128x64.
// LDS: 2 bufs x {A0,A1,B0,B1} halves. Per tile:
//   vmcnt(6); BAR | ph0: rd af0,b01; stg A1(T+1)->nbuf; q00 | BAR
//   ph1: rd b23; stg A0,B0(T+2)->buf; q01 | BAR
//   ph2: rd af1; stg B1(T+2)->buf; q10+q11
#define BARF asm volatile("s_barrier" ::: "memory")

#define STGH(srcH, kOff, dstE)                                                  \
  __builtin_amdgcn_global_load_lds(                                             \
      (const __attribute__((address_space(1))) void*)((srcH) + (kOff)),         \
      (__attribute__((address_space(3))) void*)(&smem[dstE]), 16, 0, 0);        \
  __builtin_amdgcn_global_load_lds(                                             \
      (const __attribute__((address_space(1))) void*)((srcH) + 32768 + (kOff)), \
      (__attribute__((address_space(3))) void*)(&smem[(dstE) + 512]), 16, 0, 0)

#define Q(ACCR, ACCC, AF_, BF_)                                                 \
  _Pragma("unroll") for (int kk = 0; kk < 2; ++kk)                              \
    _Pragma("unroll") for (int m = 0; m < 4; ++m)                               \
      _Pragma("unroll") for (int n = 0; n < 2; ++n)                             \
        acc[(ACCR) + m][(ACCC) + n] =                                           \
            MFMA_BF16(AF_[m][kk], BF_[n][kk], acc[(ACCR) + m][(ACCC) + n], 0, 0, 0);

#define TILE(bufE_, nbufE_, kA1_, kT2_, ST_A1, ST_T2, VMC)                       \
  {                                                                              \
    if ((VMC) == 6) asm volatile("s_waitcnt vmcnt(6)" ::: "memory");             \
    else            asm volatile("s_waitcnt vmcnt(0)" ::: "memory");             \
    BARF;  /* all waves' tile-T halves DMA-visible */                            \
    bf16x8 af0[4][2], af1[4][2], b01[2][2], b23[2][2];                           \
    /* ph0 */                                                                    \
    _Pragma("unroll") for (int m = 0; m < 4; ++m) {                              \
      af0[m][0] = *(const bf16x8*)&smem[(bufE_) + aR + m * 1024 + colE0];        \
      af0[m][1] = *(const bf16x8*)&smem[(bufE_) + aR + m * 1024 + colE1];        \
    }                                                                            \
    _Pragma("unroll") for (int n = 0; n < 2; ++n) {                              \
      b01[n][0] = *(const bf16x8*)&smem[(bufE_) + 16384 + bR + n * 1024 + colE0];\
      b01[n][1] = *(const bf16x8*)&smem[(bufE_) + 16384 + bR + n * 1024 + colE1];\
    }                                                                            \
    if (ST_A1) { STGH(aSrcH1, kA1_, (nbufE_) + 8192 + dstW); }                   \
    __builtin_amdgcn_s_setprio(1);                                               \
    Q(0, 0, af0, b01);                                                           \
    __builtin_amdgcn_s_setprio(0);                                               \
    BARF;  /* ph0 reads consumed -> safe to restage A0,B0 */                     \
    /* ph1 */                                                                    \
    _Pragma("unroll") for (int n = 0; n < 2; ++n) {                              \
      b23[n][0] = *(const bf16x8*)&smem[(bufE_) + 24576 + bR + n * 1024 + colE0];\
      b23[n][1] = *(const bf16x8*)&smem[(bufE_) + 24576 + bR + n * 1024 + colE1];\
    }                                                                            \
    if (ST_T2) {                                                                 \
      STGH(aSrcH0, kT2_, (bufE_) + dstW);                                        \
      STGH(bSrcH0, kT2_, (bufE_) + 16384 + dstW);                                \
    }                                                                            \
    __builtin_amdgcn_s_setprio(1);                                               \
    Q(0, 2, af0, b23);                                                           \
    __builtin_amdgcn_s_setprio(0);                                               \
    BARF;  /* ph1 reads consumed -> safe to restage B1 */                        \
    /* ph2 */                                                                    \
    _Pragma("unroll") for (int m = 0; m < 4; ++m) {                              \
      af1[m][0] = *(const bf16x8*)&smem[(bufE_) + 8192 + aR + m * 1024 + colE0]; \
      af1[m][1] = *(const bf16x8*)&smem[(bufE_) + 8192 + aR + m * 1024 + colE1]; \
    }                                                                            \
    if (ST_T2) { STGH(bSrcH1, kT2_, (bufE_) + 24576 + dstW); }                   \
    __builtin_amdgcn_s_setprio(1);                                               \
    Q(4, 0, af1, b01);                                                           \
    Q(4, 2, af1, b23);                                                           \
    __builtin_amdgcn_s_setprio(0);                                               \
  }

__global__ __launch_bounds__(512, 2)
void lstm_gemm_kernel(const ushort* __restrict__ A, const ushort* __restrict__ Wp,
                      const float* __restrict__ c,
                      const float* __restrict__ bii, const float* __restrict__ bif_,
                      const float* __restrict__ big_, const float* __restrict__ bio_,
                      const float* __restrict__ bhi, const float* __restrict__ bhf,
                      const float* __restrict__ bhg, const float* __restrict__ bho,
                      float* __restrict__ out) {
  __shared__ ushort smem[65536];  // 2 bufs x {A0,A1,B0,B1} halves x 16 KiB = 128 KiB
  const int tid = threadIdx.x;
  const int lane = tid & 63, w = tid >> 6;
  const int wm = w >> 2, wn = w & 3;

  // bn-major XCD mapping: XCD x owns bn in [x*4, x*4+4) x all 16 bm.
  const int bid = blockIdx.x;
  const int xcd = bid & 7, qq = bid >> 3;
  const int bn = (xcd << 2) | (qq >> 4);
  const int bm = qq & 15;

  const int laneRow = lane & 15, lane16 = lane >> 4;
  const int lr7 = laneRow & 7;
  const int colE0 = (lane16 ^ lr7) << 3;         // elem offset within 64-el row, kk=0
  const int colE1 = ((4 + lane16) ^ lr7) << 3;   // kk=1

  // DMA: lane l -> half-row (l>>3), phys chunk l&7 holding logical chunk
  // (l&7)^((l>>3)&7) -> pre-swizzled global source (proven 0-conflict scheme).
  const int chunkOff = ((lane & 7) ^ (lane >> 3)) << 3;
  const ushort* aSrcH0 = A + (size_t)(bm * 256 + 16 * w + (lane >> 3)) * 4096 + chunkOff;
  const ushort* aSrcH1 = aSrcH0 + (size_t)128 * 4096;
  const ushort* bSrcH0 = Wp + (size_t)(bn * 256 + 16 * w + (lane >> 3)) * 4096 + chunkOff;
  const ushort* bSrcH1 = bSrcH0 + (size_t)128 * 4096;
  const int dstW = w * 1024;  // wave's 16 rows within a half

  const int aR = (wm * 64 + laneRow) * 64;   // + buf + half + m*1024 + colE
  const int bR = (wn * 32 + laneRow) * 64;   // + buf + half + n*1024 + colE

  f32x4 acc[8][4];
#pragma unroll
  for (int i = 0; i < 8; i++)
#pragma unroll
    for (int j = 0; j < 4; j++) acc[i][j] = (f32x4){0.f, 0.f, 0.f, 0.f};

  // Prologue: T0 all 4 halves (8 loads) then T1's A0,B0,B1 (6 loads).
  // First TILE's vmcnt(6) retires exactly T0's 8.
  STGH(aSrcH0, 0, dstW);                  // A0(0)
  STGH(bSrcH0, 0, 16384 + dstW);          // B0(0)
  STGH(bSrcH1, 0, 24576 + dstW);          // B1(0)
  STGH(aSrcH1, 0, 8192 + dstW);           // A1(0)
  STGH(aSrcH0, 64, 32768 + dstW);         // A0(1)
  STGH(bSrcH0, 64, 32768 + 16384 + dstW); // B0(1)
  STGH(bSrcH1, 64, 32768 + 24576 + dstW); // B1(1)

#pragma unroll 1
  for (int T = 0; T < 62; T += 2) {
    const int kA = (T + 1) << 6, kB = (T + 2) << 6, kC = (T + 3) << 6;
    TILE(0, 32768, kA, kB, true, true, 6);
    TILE(32768, 0, kB, kC, true, true, 6);
  }
  TILE(0, 32768, 63 << 6, 0, true, false, 6);   // T=62: stage A1(63) only
  TILE(32768, 0, 0, 0, false, false, 0);        // T=63: drain

  // Fused LSTM epilogue: acc[mi][gate][rr] register-local per (row, hcol).
  const int hcol = bn * 64 + wn * 16 + laneRow;
  const float bI = bii[hcol] + bhi[hcol];
  const float bF = bif_[hcol] + bhf[hcol];
  const float bG = big_[hcol] + bhg[hcol];
  const float bO = bio_[hcol] + bho[hcol];
#pragma unroll
  for (int mi = 0; mi < 8; ++mi) {
    const int rowBase = bm * 256 + (mi >> 2) * 128 + wm * 64 + (mi & 3) * 16 + lane16 * 4;
#pragma unroll
    for (int rr = 0; rr < 4; ++rr) {
      const int row = rowBase + rr;
      const float ii = acc[mi][0][rr] + bI;
      const float ff = acc[mi][1][rr] + bF;
      const float gg = acc[mi][2][rr] + bG;
      const float oo = acc[mi][3][rr] + bO;
      const float iv = 1.f / (1.f + __expf(-ii));
      const float fv = 1.f / (1.f + __expf(-ff));
      const float gv = tanhf(gg);
      const float ov = 1.f / (1.f + __expf(-oo));
      const float cv = c[(size_t)row * 2048 + hcol];
      const float cn = fv * cv + iv * gv;
      const float hn = ov * tanhf(cn);
      out[(size_t)row * 2048 + hcol] = hn;
      out[(size_t)8388608 + (size_t)row * 2048 + hcol] = cn;
    }
  }
}

extern "C" void kernel_launch(void* const* d_in, const int* in_sizes, int n_in,
                              void* d_out, int out_size, void* d_ws, size_t ws_size,
                              hipStream_t stream) {
  const float* x = (const float*)d_in[0];
  const float* h = (const float*)d_in[1];
  const float* c = (const float*)d_in[2];
  const float* Wii = (const float*)d_in[3];  const float* bii = (const float*)d_in[4];
  const float* Wif = (const float*)d_in[5];  const float* bif_ = (const float*)d_in[6];
  const float* Wig = (const float*)d_in[7];  const float* big_ = (const float*)d_in[8];
  const float* Wio = (const float*)d_in[9];  const float* bio_ = (const float*)d_in[10];
  const float* Whi = (const float*)d_in[11]; const float* bhi = (const float*)d_in[12];
  const float* Whf = (const float*)d_in[13]; const float* bhf = (const float*)d_in[14];
  const float* Whg = (const float*)d_in[15]; const float* bhg = (const float*)d_in[16];
  const float* Who = (const float*)d_in[17]; const float* bho = (const float*)d_in[18];

  ushort* Abf = (ushort*)d_ws;                    // 4096*4096 bf16
  ushort* Wpk = Abf + (size_t)4096 * 4096;        // 8192*4096 bf16
  float* out = (float*)d_out;

  pack_all_kernel<<<3072, 256, 0, stream>>>((const float4*)x, (const float4*)h,
                                            Wii, Wif, Wig, Wio, Whi, Whf, Whg, Who,
                                            (bf16x8*)Abf, (bf16x8*)Wpk);
  lstm_gemm_kernel<<<512, 512, 0, stream>>>(Abf, Wpk, c,
                                            bii, bif_, big_, bio_, bhi, bhf, bhg, bho, out);
}